// Round 1
// baseline (473.701 us; speedup 1.0000x reference)
//
#include <hip/hip_runtime.h>
#include <math.h>

#define B_  32
#define C_  256
#define T_  64      // 8*8 pooled tokens
#define HW_ 4096    // 64*64 plane

// ---------------- Kernel 1: 8x8 average pool, wave-per-plane, shuffle reduce ----------------
// Each wave owns one (b,c) plane of one tensor pair. 16 float4 loads per tensor issued
// back-to-back (no LDS, no barriers), then a shfl_xor tree reduces each 8x8 cell.
// Chunk q (64 float4): lane covers rows 4q..4q+3 (cy=q/2), cx=(lane&15)/2.
// Lanes {16r+2cx+e} hold one cell's 64 values after pairing chunks 2m,2m+1.
__device__ __forceinline__ float pool_plane(const float4* __restrict__ p, int lane) {
    float4 v[16];
    #pragma unroll
    for (int q = 0; q < 16; ++q) v[q] = p[q*64 + lane];
    float res = 0.f;
    #pragma unroll
    for (int m = 0; m < 8; ++m) {
        float s = (v[2*m].x + v[2*m].y + v[2*m].z + v[2*m].w)
                + (v[2*m+1].x + v[2*m+1].y + v[2*m+1].z + v[2*m+1].w);
        s += __shfl_xor(s, 1);    // combine x-halves (e)
        s += __shfl_xor(s, 16);   // combine row groups
        s += __shfl_xor(s, 32);
        // lane 2*cx now holds cell(m, cx); gather so lane (m*8+cx) keeps it
        float g = __shfl(s, 2*(lane & 7));
        res = ((lane >> 3) == m) ? g : res;
    }
    return res * (1.f/64.f);
}

__global__ __launch_bounds__(256) void k_pool(const float* __restrict__ Frgb,
                                              const float* __restrict__ Fd,
                                              float* __restrict__ R,
                                              float* __restrict__ D) {
    const int lane  = threadIdx.x & 63;
    const int plane = (blockIdx.x << 2) + (threadIdx.x >> 6);   // 2048 blocks * 4 waves
    const float4* pa = (const float4*)Frgb + (size_t)plane * 1024;
    const float4* pb = (const float4*)Fd   + (size_t)plane * 1024;
    R[(size_t)plane*64 + lane] = pool_plane(pa, lane);
    D[(size_t)plane*64 + lane] = pool_plane(pb, lane);
}

// ---------------- Kernel 2a: Q/K/V = W @ X + bias ----------------
// grid: (4 t-tiles, 32 batches, 3 {Q,K,V}), 256 threads. Thread owns output channel o=tid,
// accumulates a 16-wide t-tile. W staged COALESCED: 8 lanes per 128B row segment,
// transposed into LDS with +1-ish padding (stride 257 -> bank (c+o)%32, conflict-free reads).
__global__ __launch_bounds__(256) void k_qkv(const float* __restrict__ R, const float* __restrict__ D,
                                             const float* __restrict__ Wq, const float* __restrict__ bq,
                                             const float* __restrict__ Wk, const float* __restrict__ bk,
                                             const float* __restrict__ Wv, const float* __restrict__ bv,
                                             float* __restrict__ Q, float* __restrict__ K,
                                             float* __restrict__ V) {
    __shared__ float Ws[32 * 257];   // [c_local][o], padded
    const int tid = threadIdx.x;
    const int tbase = blockIdx.x * 16;
    const int b = blockIdx.y;
    const int z = blockIdx.z;
    const float* W    = (z == 0) ? Wq : (z == 1) ? Wk : Wv;
    const float* bias = (z == 0) ? bq : (z == 1) ? bk : bv;
    const float* X    = (z == 0) ? R  : D;
    float* Out        = (z == 0) ? Q  : (z == 1) ? K  : V;

    const int o = tid;
    float acc[16];
    const float bz = bias[o];
    #pragma unroll
    for (int t = 0; t < 16; ++t) acc[t] = bz;

    const float* Xb = X + (size_t)b * C_ * T_;
    const int orow = tid >> 3;          // staging row within a 32-row pass
    const int c4   = (tid & 7) * 4;     // staging col (float4)
    for (int cb = 0; cb < 256; cb += 32) {
        __syncthreads();
        #pragma unroll
        for (int p = 0; p < 8; ++p) {
            const int orr = orow + p*32;
            float4 w4 = *(const float4*)(W + (size_t)orr * 256 + cb + c4);
            Ws[(c4 + 0)*257 + orr] = w4.x;
            Ws[(c4 + 1)*257 + orr] = w4.y;
            Ws[(c4 + 2)*257 + orr] = w4.z;
            Ws[(c4 + 3)*257 + orr] = w4.w;
        }
        __syncthreads();
        for (int cl = 0; cl < 32; ++cl) {
            const float w = Ws[cl*257 + o];
            const float* xrow = Xb + (size_t)(cb + cl) * T_ + tbase;  // wave-uniform -> s_load
            #pragma unroll
            for (int t = 0; t < 16; ++t) acc[t] = fmaf(w, xrow[t], acc[t]);
        }
    }
    float* orowp = Out + ((size_t)b * C_ + o) * T_ + tbase;
    #pragma unroll
    for (int t4 = 0; t4 < 4; ++t4)
        *(float4*)(orowp + t4*4) = make_float4(acc[t4*4+0], acc[t4*4+1], acc[t4*4+2], acc[t4*4+3]);
}

// ---------------- Kernel 2b: per-batch A = softmax(Q^T K) fused with Fatt = V A^T ---------
// grid: 32 blocks (one per batch), 256 threads (4 waves).
// Phase 1: A[t][s] = sum_c Q[c,t] K[c,s]; lane = s, wave owns a 16-row t-tile.
// Softmax over s in registers (64-lane butterflies) -> As[s][t] in LDS.
// Phase 2 (fused PV): wave wv owns c in [wv*64, wv*64+64): Fatt[c][t] = sum_s V[c][s]*A[t][s].
// Fatt aliases the (dead) Q buffer -> no __restrict__ on Q/Fatt.
__global__ __launch_bounds__(256) void k_attnA(const float* Q,
                                               const float* __restrict__ K,
                                               const float* __restrict__ V,
                                               float* Fatt) {
    __shared__ float Ks[128 * 64];   // half of K[b], 32 KB
    __shared__ float As[64 * 65];    // A transposed [s][t], pad 65
    const int tid  = threadIdx.x;
    const int lane = tid & 63;
    const int wv   = __builtin_amdgcn_readfirstlane(tid >> 6);
    const int b = blockIdx.x;

    float acc[16];
    #pragma unroll
    for (int t = 0; t < 16; ++t) acc[t] = 0.f;

    const float* Qb = Q + (size_t)b * C_ * T_;
    const float* Kb = K + (size_t)b * C_ * T_;
    for (int half = 0; half < 2; ++half) {
        __syncthreads();
        const float4* src = (const float4*)(Kb + half * 128 * 64);
        float4* dst = (float4*)Ks;
        #pragma unroll
        for (int k = 0; k < 8; ++k) dst[k*256 + tid] = src[k*256 + tid];
        __syncthreads();
        for (int cl = 0; cl < 128; ++cl) {
            const float kv = Ks[cl*64 + lane];
            const float* qrow = Qb + (size_t)(half*128 + cl) * T_ + wv*16;  // wave-uniform
            #pragma unroll
            for (int t = 0; t < 16; ++t) acc[t] = fmaf(kv, qrow[t], acc[t]);
        }
    }

    #pragma unroll
    for (int t = 0; t < 16; ++t) {
        float m = acc[t];
        #pragma unroll
        for (int off = 32; off; off >>= 1) m = fmaxf(m, __shfl_xor(m, off));
        const float e = __expf(acc[t] - m);
        float ssum = e;
        #pragma unroll
        for (int off = 32; off; off >>= 1) ssum += __shfl_xor(ssum, off);
        As[lane*65 + wv*16 + t] = e / ssum;
    }
    __syncthreads();

    // -------- fused PV --------
    float at[64];                       // column t of A (for all s), conflict-free (s+lane)%32
    #pragma unroll
    for (int s = 0; s < 64; ++s) at[s] = As[s*65 + lane];
    const float* Vb = V + (size_t)b * C_ * T_;
    float* Fb = Fatt + (size_t)b * C_ * T_;
    for (int j = 0; j < 64; ++j) {
        const int c = wv*64 + j;                    // wave-uniform
        const float* vr = Vb + (size_t)c * T_;      // uniform row -> scalar loads
        float sum = 0.f;
        #pragma unroll
        for (int s = 0; s < 64; ++s) sum = fmaf(vr[s], at[s], sum);
        Fb[(size_t)c * T_ + lane] = sum;            // coalesced 256B per wave
    }
}

// ---------------- Kernel 3: bilinear 8->64 upsample + blend (streaming) ----------------
// grid: B*C blocks (one per plane), 256 threads. PV already done -> just read 64 floats.
// rgb loads issued before the barrier so HBM streaming overlaps the Fatt fetch.
__global__ __launch_bounds__(256) void k_up(const float* __restrict__ Fatt,
                                            const float* __restrict__ Frgb,
                                            const float* __restrict__ alphap,
                                            float* __restrict__ Out) {
    __shared__ float Fs[64];
    const int tid = threadIdx.x;
    const int plane = blockIdx.x;
    const float4* rgb4 = (const float4*)Frgb + (size_t)plane * 1024;
    float4 rv[4];
    #pragma unroll
    for (int k = 0; k < 4; ++k) rv[k] = rgb4[k*256 + tid];
    if (tid < 64) Fs[tid] = Fatt[(size_t)plane*64 + tid];
    __syncthreads();

    const float alpha = alphap[0];
    const float beta = 1.f - alpha;
    float4* out4 = (float4*)Out + (size_t)plane * 1024;
    #pragma unroll
    for (int k = 0; k < 4; ++k) {
        const int flat = k*1024 + tid*4;
        const int y  = flat >> 6;
        const int xb = flat & 63;
        const float sy = y * 0.125f - 0.4375f;
        const float fy = floorf(sy);
        const float wy = sy - fy;
        const int iy = (int)fy;
        const int y0 = iy < 0 ? 0 : iy;
        const int y1 = (iy + 1) > 7 ? 7 : (iy + 1);
        const float rs[4] = {rv[k].x, rv[k].y, rv[k].z, rv[k].w};
        float o[4];
        #pragma unroll
        for (int j = 0; j < 4; ++j) {
            const int x = xb + j;
            const float sx = x * 0.125f - 0.4375f;
            const float fx = floorf(sx);
            const float wx = sx - fx;
            const int ix = (int)fx;
            const int x0 = ix < 0 ? 0 : ix;
            const int x1 = (ix + 1) > 7 ? 7 : (ix + 1);
            const float top = (1.f - wx) * Fs[y0*8 + x0] + wx * Fs[y0*8 + x1];
            const float bot = (1.f - wx) * Fs[y1*8 + x0] + wx * Fs[y1*8 + x1];
            const float v = (1.f - wy) * top + wy * bot;
            o[j] = alpha * v + beta * rs[j];
        }
        out4[k*256 + tid] = make_float4(o[0], o[1], o[2], o[3]);
    }
}

extern "C" void kernel_launch(void* const* d_in, const int* in_sizes, int n_in,
                              void* d_out, int out_size, void* d_ws, size_t ws_size,
                              hipStream_t stream) {
    const float* Frgb  = (const float*)d_in[0];
    const float* Fd    = (const float*)d_in[1];
    const float* Wq    = (const float*)d_in[2];
    const float* bq    = (const float*)d_in[3];
    const float* Wk    = (const float*)d_in[4];
    const float* bk    = (const float*)d_in[5];
    const float* Wv    = (const float*)d_in[6];
    const float* bv    = (const float*)d_in[7];
    const float* alpha = (const float*)d_in[8];

    float* ws = (float*)d_ws;
    const size_t PC = (size_t)B_ * C_ * T_;   // 524288 floats per pooled tensor
    float* R    = ws;
    float* D    = ws + PC;
    float* Q    = ws + 2*PC;
    float* K    = ws + 3*PC;
    float* V    = ws + 4*PC;
    float* Fatt = Q;                          // Q is dead after k_attnA's QK phase (per-block safe)
    float* Out  = (float*)d_out;

    k_pool <<<2048, 256, 0, stream>>>(Frgb, Fd, R, D);
    k_qkv  <<<dim3(4, 32, 3), 256, 0, stream>>>(R, D, Wq, bq, Wk, bk, Wv, bv, Q, K, V);
    k_attnA<<<B_, 256, 0, stream>>>(Q, K, V, Fatt);
    k_up   <<<B_*C_, 256, 0, stream>>>(Fatt, Frgb, alpha, Out);
}

// Round 3
// 397.943 us; speedup vs baseline: 1.1904x; 1.1904x over previous
//
#include <hip/hip_runtime.h>
#include <math.h>

#define B_  32
#define C_  256
#define T_  64      // 8*8 pooled tokens
#define HW_ 4096    // 64*64 plane

// ---------------- Kernel 1: 8x8 average pool, one tensor per dispatch ----------------
// grid: B*C blocks, 256 threads, one (b,c) plane each. Register partials -> LDS -> 64-thread gather.
// Split per tensor so rocprof top-5 resolves the per-kernel decomposition.
__global__ __launch_bounds__(256) void k_pool1(const float* __restrict__ In,
                                               float* __restrict__ Outp) {
    __shared__ float P[1024];
    const int tid = threadIdx.x;
    const int plane = blockIdx.x;
    const float4* p = (const float4*)In + (size_t)plane * 1024;
    #pragma unroll
    for (int k = 0; k < 4; ++k) {
        float4 a = p[k*256 + tid];
        P[k*256 + tid] = a.x + a.y + a.z + a.w;
    }
    __syncthreads();
    // cell (cy,cx): contributing partials at idx = (cy>>1)*256 + (cy&1)*128 + 2cx + rg*16 + e
    if (tid < 64) {
        const int cy = tid >> 3, cx = tid & 7;
        const int base = (cy >> 1)*256 + (cy & 1)*128 + 2*cx;
        float s = 0.f;
        #pragma unroll
        for (int rg = 0; rg < 8; ++rg)
            s += P[base + rg*16] + P[base + rg*16 + 1];
        Outp[(size_t)plane*64 + tid] = s * (1.f/64.f);
    }
}

// ---------------- Kernel 2a: Q/K/V = W @ X + bias ----------------
// grid: (8 t-tiles, 32 batches, 3 {Q,K,V}) = 768 blocks -> 3 blocks (12 waves)/CU for
// latency hiding (was 1.5 blocks/CU). Thread owns output channel o=tid, 8-wide t-tile.
// W staged coalesced (8 lanes per 128B row segment), transposed into padded LDS (stride 257).
__global__ __launch_bounds__(256) void k_qkv(const float* __restrict__ R, const float* __restrict__ D,
                                             const float* __restrict__ Wq, const float* __restrict__ bq,
                                             const float* __restrict__ Wk, const float* __restrict__ bk,
                                             const float* __restrict__ Wv, const float* __restrict__ bv,
                                             float* __restrict__ Q, float* __restrict__ K,
                                             float* __restrict__ V) {
    __shared__ float Ws[32 * 257];   // [c_local][o], padded
    const int tid = threadIdx.x;
    const int tbase = blockIdx.x * 8;
    const int b = blockIdx.y;
    const int z = blockIdx.z;
    const float* W    = (z == 0) ? Wq : (z == 1) ? Wk : Wv;
    const float* bias = (z == 0) ? bq : (z == 1) ? bk : bv;
    const float* X    = (z == 0) ? R  : D;
    float* Out        = (z == 0) ? Q  : (z == 1) ? K  : V;

    const int o = tid;
    float acc[8];
    const float bz = bias[o];
    #pragma unroll
    for (int t = 0; t < 8; ++t) acc[t] = bz;

    const float* Xb = X + (size_t)b * C_ * T_;
    const int orow = tid >> 3;          // staging row within a 32-row pass
    const int c4   = (tid & 7) * 4;     // staging col (float4)
    for (int cb = 0; cb < 256; cb += 32) {
        __syncthreads();
        #pragma unroll
        for (int p = 0; p < 8; ++p) {
            const int orr = orow + p*32;
            float4 w4 = *(const float4*)(W + (size_t)orr * 256 + cb + c4);
            Ws[(c4 + 0)*257 + orr] = w4.x;
            Ws[(c4 + 1)*257 + orr] = w4.y;
            Ws[(c4 + 2)*257 + orr] = w4.z;
            Ws[(c4 + 3)*257 + orr] = w4.w;
        }
        __syncthreads();
        for (int cl = 0; cl < 32; ++cl) {
            const float w = Ws[cl*257 + o];
            const float* xrow = Xb + (size_t)(cb + cl) * T_ + tbase;  // wave-uniform -> s_load
            #pragma unroll
            for (int t = 0; t < 8; ++t) acc[t] = fmaf(w, xrow[t], acc[t]);
        }
    }
    float* orowp = Out + ((size_t)b * C_ + o) * T_ + tbase;
    *(float4*)(orowp + 0) = make_float4(acc[0], acc[1], acc[2], acc[3]);
    *(float4*)(orowp + 4) = make_float4(acc[4], acc[5], acc[6], acc[7]);
}

// ---------------- Kernel 2b: per-batch A = softmax(Q^T K), stored transposed ----------------
// grid: 32 blocks (one per batch), 512 threads (8 waves -> 2 waves/SIMD on its CUs).
// A[t][s] = sum_c Q[c,t] K[c,s]; lane = s, wave owns an 8-row t-tile.
// Softmax over s in registers (64-lane butterflies). Output AT[b][s][t].
__global__ __launch_bounds__(512) void k_attnA(const float* __restrict__ Q,
                                               const float* __restrict__ K,
                                               float* __restrict__ AT) {
    __shared__ float Ks[128 * 64];   // half of K[b], 32 KB
    __shared__ float As[64 * 65];    // A transposed [s][t], pad 65
    const int tid  = threadIdx.x;
    const int lane = tid & 63;
    const int wv   = __builtin_amdgcn_readfirstlane(tid >> 6);   // 0..7
    const int b = blockIdx.x;

    float acc[8];
    #pragma unroll
    for (int t = 0; t < 8; ++t) acc[t] = 0.f;

    const float* Qb = Q + (size_t)b * C_ * T_;
    const float* Kb = K + (size_t)b * C_ * T_;
    for (int half = 0; half < 2; ++half) {
        __syncthreads();
        const float4* src = (const float4*)(Kb + half * 128 * 64);
        float4* dst = (float4*)Ks;
        #pragma unroll
        for (int k = 0; k < 4; ++k) dst[k*512 + tid] = src[k*512 + tid];
        __syncthreads();
        for (int cl = 0; cl < 128; ++cl) {
            const float kv = Ks[cl*64 + lane];
            const float* qrow = Qb + (size_t)(half*128 + cl) * T_ + wv*8;  // wave-uniform
            #pragma unroll
            for (int t = 0; t < 8; ++t) acc[t] = fmaf(kv, qrow[t], acc[t]);
        }
    }

    #pragma unroll
    for (int t = 0; t < 8; ++t) {
        float m = acc[t];
        #pragma unroll
        for (int off = 32; off; off >>= 1) m = fmaxf(m, __shfl_xor(m, off));
        const float e = __expf(acc[t] - m);
        float ssum = e;
        #pragma unroll
        for (int off = 32; off; off >>= 1) ssum += __shfl_xor(ssum, off);
        As[lane*65 + wv*8 + t] = e / ssum;
    }
    __syncthreads();

    // coalesced write-out of AT[b][s][t]
    float* ATb = AT + (size_t)b * T_ * T_;
    #pragma unroll
    for (int i = 0; i < 8; ++i) {
        const int idx = i*512 + tid;
        const int s = idx >> 6, t = idx & 63;
        ATb[idx] = As[s*65 + t];
    }
}

// ---------------- Kernel 3: PV + bilinear 8->64 upsample + blend (fused) ----------------
// grid: B*C blocks (one per plane), 256 threads.
// Fatt[t] = sum_s V[b,c,s] * AT[b][s][t]   (AT is 0.5 MB total -> L2-hot)
// rgb loads issued FIRST so the HBM stream overlaps PV's L2 latency.
__global__ __launch_bounds__(256) void k_up(const float* __restrict__ AT,
                                            const float* __restrict__ V,
                                            const float* __restrict__ Frgb,
                                            const float* __restrict__ alphap,
                                            float* __restrict__ Out) {
    __shared__ float Vs[64];
    __shared__ float Ps[4][64];
    __shared__ float Fs[64];
    const int tid = threadIdx.x;
    const int plane = blockIdx.x;
    const int b = plane >> 8;

    const float4* rgb4 = (const float4*)Frgb + (size_t)plane * 1024;
    float4 rv[4];
    #pragma unroll
    for (int k = 0; k < 4; ++k) rv[k] = rgb4[k*256 + tid];   // in flight during PV

    if (tid < 64) Vs[tid] = V[(size_t)plane*64 + tid];
    __syncthreads();
    // PV: thread (sq=tid>>6, t=tid&63) sums 16 s values
    {
        const int t = tid & 63;
        const int sq = tid >> 6;
        const float* ATb = AT + (size_t)b * T_ * T_;
        float sum = 0.f;
        #pragma unroll
        for (int j = 0; j < 16; ++j) {
            const int s = sq*16 + j;
            sum = fmaf(Vs[s], ATb[s*64 + t], sum);   // coalesced, L2-hot
        }
        Ps[sq][t] = sum;
    }
    __syncthreads();
    if (tid < 64) Fs[tid] = Ps[0][tid] + Ps[1][tid] + Ps[2][tid] + Ps[3][tid];
    __syncthreads();

    const float alpha = alphap[0];
    const float beta = 1.f - alpha;
    float4* out4 = (float4*)Out + (size_t)plane * 1024;
    #pragma unroll
    for (int k = 0; k < 4; ++k) {
        const int flat = k*1024 + tid*4;
        const int y  = flat >> 6;
        const int xb = flat & 63;
        const float sy = y * 0.125f - 0.4375f;
        const float fy = floorf(sy);
        const float wy = sy - fy;
        const int iy = (int)fy;
        const int y0 = iy < 0 ? 0 : iy;
        const int y1 = (iy + 1) > 7 ? 7 : (iy + 1);
        const float rs[4] = {rv[k].x, rv[k].y, rv[k].z, rv[k].w};
        float o[4];
        #pragma unroll
        for (int j = 0; j < 4; ++j) {
            const int x = xb + j;
            const float sx = x * 0.125f - 0.4375f;
            const float fx = floorf(sx);
            const float wx = sx - fx;
            const int ix = (int)fx;
            const int x0 = ix < 0 ? 0 : ix;
            const int x1 = (ix + 1) > 7 ? 7 : (ix + 1);
            const float top = (1.f - wx) * Fs[y0*8 + x0] + wx * Fs[y0*8 + x1];
            const float bot = (1.f - wx) * Fs[y1*8 + x0] + wx * Fs[y1*8 + x1];
            const float v = (1.f - wy) * top + wy * bot;
            o[j] = alpha * v + beta * rs[j];
        }
        out4[k*256 + tid] = make_float4(o[0], o[1], o[2], o[3]);
    }
}

extern "C" void kernel_launch(void* const* d_in, const int* in_sizes, int n_in,
                              void* d_out, int out_size, void* d_ws, size_t ws_size,
                              hipStream_t stream) {
    const float* Frgb  = (const float*)d_in[0];
    const float* Fd    = (const float*)d_in[1];
    const float* Wq    = (const float*)d_in[2];
    const float* bq    = (const float*)d_in[3];
    const float* Wk    = (const float*)d_in[4];
    const float* bk    = (const float*)d_in[5];
    const float* Wv    = (const float*)d_in[6];
    const float* bv    = (const float*)d_in[7];
    const float* alpha = (const float*)d_in[8];

    float* ws = (float*)d_ws;
    const size_t PC = (size_t)B_ * C_ * T_;   // 524288 floats per pooled tensor
    float* R    = ws;
    float* D    = ws + PC;
    float* Q    = ws + 2*PC;
    float* K    = ws + 3*PC;
    float* V    = ws + 4*PC;
    float* AT   = ws + 5*PC;                  // 32*64*64 floats
    float* Out  = (float*)d_out;

    k_pool1<<<B_*C_, 256, 0, stream>>>(Frgb, R);
    k_pool1<<<B_*C_, 256, 0, stream>>>(Fd,   D);
    k_qkv  <<<dim3(8, 32, 3), 256, 0, stream>>>(R, D, Wq, bq, Wk, bk, Wv, bv, Q, K, V);
    k_attnA<<<B_, 512, 0, stream>>>(Q, K, AT);
    k_up   <<<B_*C_, 256, 0, stream>>>(AT, V, Frgb, alpha, Out);
}